// Round 5
// baseline (387.870 us; speedup 1.0000x reference)
//
#include <hip/hip_runtime.h>

typedef unsigned short ushort_t;
typedef unsigned int   uint32;
typedef __attribute__((ext_vector_type(8)))  short short8;    // 8 x bf16 (4 VGPRs)
typedef __attribute__((ext_vector_type(4)))  float floatx4;
typedef __attribute__((ext_vector_type(16))) float floatx16;  // 32x32 MFMA accumulator

#define IN_F   4096
#define OUT_F  8192
#define M_TOT  512

__device__ __forceinline__ ushort_t f2bf(float f) {
    uint32 u = __builtin_bit_cast(uint32, f);
    u += 0x7FFFu + ((u >> 16) & 1u);    // RNE
    return (ushort_t)(u >> 16);
}
__device__ __forceinline__ uint32 pack2bf(float a, float b) {
    return (uint32)f2bf(a) | ((uint32)f2bf(b) << 16);
}

// ---------------------------------------------------------------------------
// Kernel 0: x fp32 -> bf16 into workspace (4 MB).
__global__ void cvt_x_kernel(const float* __restrict__ x, ushort_t* __restrict__ xb) {
    int i = (blockIdx.x * 256 + threadIdx.x) * 8;
    float4 v0 = *(const float4*)(x + i);
    float4 v1 = *(const float4*)(x + i + 4);
    short8 s;
    s[0] = (short)f2bf(v0.x); s[1] = (short)f2bf(v0.y);
    s[2] = (short)f2bf(v0.z); s[3] = (short)f2bf(v0.w);
    s[4] = (short)f2bf(v1.x); s[5] = (short)f2bf(v1.y);
    s[6] = (short)f2bf(v1.z); s[7] = (short)f2bf(v1.w);
    *(short8*)(xb + i) = s;
}

// ---------------------------------------------------------------------------
// Kernel 1: dequant W -> bf16 [OUT_F][IN_F]. grid (256,2): block (bx,by) owns
// rows [bx*32,+32), k in [by*2048,+2048). 512 blocks -> queue balancing across
// the LDS-gated (1 block/CU) residency. Depth-2 software pipeline, fully
// unrolled so the compiler renames registers (no vmcnt(0)-forcing rotation).
__global__ __launch_bounds__(1024, 4)
void dequant_kernel(const int* __restrict__ base_idx, const int* __restrict__ fine_idx,
                    const float* __restrict__ lut, ushort_t* __restrict__ wq)
{
    __shared__ ushort_t sh_lut[65536];   // 128 KB bf16 LUT
    const int tid = threadIdx.x;
    for (int i = tid * 4; i < 65536; i += 1024 * 4) {
        float4 v = *(const float4*)(lut + i);
        *(uint32*)&sh_lut[i]     = pack2bf(v.x, v.y);
        *(uint32*)&sh_lut[i + 2] = pack2bf(v.z, v.w);
    }

    const int row   = blockIdx.x * 32 + (tid >> 5);
    const int kbase = blockIdx.y * 2048 + (tid & 31) * 4;
    const int* bp = base_idx + (size_t)row * IN_F + kbase;
    const int* fp = fine_idx + (size_t)row * IN_F + kbase;
    ushort_t*  op = wq       + (size_t)row * IN_F + kbase;

    // 16 chunks (stride 128 elems) = 4 batches x 4 chunks, pipeline depth 2.
    int4 cb[2][4], cf[2][4];
#pragma unroll
    for (int u = 0; u < 4; ++u) {
        cb[0][u] = *(const int4*)(bp + u * 128);
        cf[0][u] = *(const int4*)(fp + u * 128);
    }
#pragma unroll
    for (int u = 0; u < 4; ++u) {
        cb[1][u] = *(const int4*)(bp + (4 + u) * 128);
        cf[1][u] = *(const int4*)(fp + (4 + u) * 128);
    }
    __syncthreads();   // LUT ready (idx loads already in flight across it)

#pragma unroll
    for (int b = 0; b < 4; ++b) {
        const int cur = b & 1;
#pragma unroll
        for (int u = 0; u < 4; ++u) {
            uint32 w0 = (uint32)sh_lut[(cb[cur][u].x << 8) + cf[cur][u].x]
                      | ((uint32)sh_lut[(cb[cur][u].y << 8) + cf[cur][u].y] << 16);
            uint32 w1 = (uint32)sh_lut[(cb[cur][u].z << 8) + cf[cur][u].z]
                      | ((uint32)sh_lut[(cb[cur][u].w << 8) + cf[cur][u].w] << 16);
            uint2 wv; wv.x = w0; wv.y = w1;
            *(uint2*)(op + (size_t)(b * 4 + u) * 128) = wv;
        }
        if (b + 2 < 4) {
#pragma unroll
            for (int u = 0; u < 4; ++u) {
                cb[cur][u] = *(const int4*)(bp + ((b + 2) * 4 + u) * 128);
                cf[cur][u] = *(const int4*)(fp + ((b + 2) * 4 + u) * 128);
            }
        }
    }
}

// ---------------------------------------------------------------------------
// Kernel 2: GEMM  out[512,8192] = xb[512,4096] * wq[8192,4096]^T  (bf16 MFMA)
// 128x128 tile, BK=128, 32x32x16 MFMA, XOR-swizzled LDS (row stride 256B).
// Double-buffered staging with ONE barrier per iter placed BEFORE the stage:
//   { __syncthreads(); stage(t+1)->buf^1; compute(t) from buf^0; }
// The barrier's implicit vmcnt(0) only drains loads issued one full compute
// phase earlier -> staging latency overlapped, no hand waitcnt needed.
#define BK 128
__global__ __launch_bounds__(256)
void gemm_kernel(const ushort_t* __restrict__ xb, const ushort_t* __restrict__ wq,
                 const float* __restrict__ scale, float* __restrict__ out)
{
    __shared__ ushort_t shA[2][128 * BK];   // 2 x 32 KB
    __shared__ ushort_t shB[2][128 * BK];   // 2 x 32 KB  -> 128 KB total

    const int tid  = threadIdx.x;
    const int wave = tid >> 6;
    const int m0   = blockIdx.x * 128;
    const int n0   = blockIdx.y * 128;

    // staging: inst i covers rows [i*16,+16); thread -> row tid>>4.
    // LDS dest (HW-fixed): wave base + lane*16 -> position chunk = lane&15.
    // Source chunk XOR-swizzled: g = (lane&15) ^ (row&7).
    const int g = (tid & 15) ^ ((tid >> 4) & 7);
    const ushort_t* aBase = xb + (size_t)(m0 + (tid >> 4)) * IN_F + g * 8;
    const ushort_t* bBase = wq + (size_t)(n0 + (tid >> 4)) * IN_F + g * 8;
    typedef __attribute__((address_space(3))) ushort_t lds_us;
    typedef const __attribute__((address_space(1))) void gvoid;
    lds_us* sA3 = (lds_us*)&shA[0][0];
    lds_us* sB3 = (lds_us*)&shB[0][0];

    const int lane = tid & 63;
    const int l31  = lane & 31;
    const int lhi  = lane >> 5;
    const int qm   = wave & 1;
    const int qn   = wave >> 1;
    const int rx   = l31 & 7;            // read-side XOR key (row&7)

    floatx16 acc[2][2];
    const floatx16 z16 = {0.f,0.f,0.f,0.f,0.f,0.f,0.f,0.f,0.f,0.f,0.f,0.f,0.f,0.f,0.f,0.f};
    acc[0][0] = z16; acc[0][1] = z16; acc[1][0] = z16; acc[1][1] = z16;

    // prologue: stage tile 0 into buf 0
#pragma unroll
    for (int i = 0; i < 8; ++i) {
        __builtin_amdgcn_global_load_lds((gvoid*)(aBase + (size_t)i * 16 * IN_F),
            (__attribute__((address_space(3))) void*)(sA3 + i * 2048 + wave * 512), 16, 0, 0);
        __builtin_amdgcn_global_load_lds((gvoid*)(bBase + (size_t)i * 16 * IN_F),
            (__attribute__((address_space(3))) void*)(sB3 + i * 2048 + wave * 512), 16, 0, 0);
    }

    const int NIT = IN_F / BK;   // 32
    for (int t = 0; t < NIT; ++t) {
        __syncthreads();   // drains loads(t) (issued one compute-phase ago)

        if (t + 1 < NIT) {
            const int buf = (t + 1) & 1;
            const size_t kb = (size_t)(t + 1) * BK;
#pragma unroll
            for (int i = 0; i < 8; ++i) {
                __builtin_amdgcn_global_load_lds((gvoid*)(aBase + (size_t)i * 16 * IN_F + kb),
                    (__attribute__((address_space(3))) void*)(sA3 + buf * 128 * BK + i * 2048 + wave * 512),
                    16, 0, 0);
                __builtin_amdgcn_global_load_lds((gvoid*)(bBase + (size_t)i * 16 * IN_F + kb),
                    (__attribute__((address_space(3))) void*)(sB3 + buf * 128 * BK + i * 2048 + wave * 512),
                    16, 0, 0);
            }
        }

        const ushort_t* wA = shA[t & 1];
        const ushort_t* wB = shB[t & 1];
#pragma unroll
        for (int ks = 0; ks < 8; ++ks) {     // K-steps of 16
            const int p = ((2 * ks + lhi) ^ rx) * 8;   // swizzled chunk -> ushort offset
            short8 a0 = *(const short8*)&wA[(qm * 64 +      l31) * BK + p];
            short8 a1 = *(const short8*)&wA[(qm * 64 + 32 + l31) * BK + p];
            short8 b0 = *(const short8*)&wB[(qn * 64 +      l31) * BK + p];
            short8 b1 = *(const short8*)&wB[(qn * 64 + 32 + l31) * BK + p];
            acc[0][0] = __builtin_amdgcn_mfma_f32_32x32x16_bf16(a0, b0, acc[0][0], 0, 0, 0);
            acc[0][1] = __builtin_amdgcn_mfma_f32_32x32x16_bf16(a0, b1, acc[0][1], 0, 0, 0);
            acc[1][0] = __builtin_amdgcn_mfma_f32_32x32x16_bf16(a1, b0, acc[1][0], 0, 0, 0);
            acc[1][1] = __builtin_amdgcn_mfma_f32_32x32x16_bf16(a1, b1, acc[1][1], 0, 0, 0);
        }
    }

    // epilogue: 32x32 C/D mapping col=lane&31, row=(reg&3)+8*(reg>>2)+4*(lane>>5)
#pragma unroll
    for (int nt = 0; nt < 2; ++nt) {
        const int col = n0 + qn * 64 + nt * 32 + l31;
        const float sc = scale[col];
#pragma unroll
        for (int mt = 0; mt < 2; ++mt) {
            const int rbase = m0 + qm * 64 + mt * 32 + 4 * lhi;
#pragma unroll
            for (int reg = 0; reg < 16; ++reg) {
                const int row = rbase + (reg & 3) + 8 * (reg >> 2);
                out[(size_t)row * OUT_F + col] = acc[mt][nt][reg] * sc;
            }
        }
    }
}

// ---------------------------------------------------------------------------
// Fallback: round-2 fused kernel (used only if workspace is too small).
#define NB  32
#define FBK 128
#define WS  136
#define NITER (IN_F / FBK)
template<bool XBF16>
__global__ __launch_bounds__(1024, 4)
void ghost_kernel(const float* __restrict__ xf, const ushort_t* __restrict__ xb,
                  const int* __restrict__ base_idx, const int* __restrict__ fine_idx,
                  const float* __restrict__ scale, const float* __restrict__ lut,
                  float* __restrict__ out)
{
    __shared__ ushort_t sh_lut[65536];
    __shared__ ushort_t sh_w[2][NB * WS];
    const int tid = threadIdx.x;
    const int n0  = blockIdx.x * NB;
    for (int i = tid * 4; i < 65536; i += 1024 * 4) {
        float4 v = *(const float4*)(lut + i);
        sh_lut[i + 0] = f2bf(v.x); sh_lut[i + 1] = f2bf(v.y);
        sh_lut[i + 2] = f2bf(v.z); sh_lut[i + 3] = f2bf(v.w);
    }
    const int sn  = tid >> 5;
    const int skq = (tid & 31) * 4;
    const int* bp = base_idx + (size_t)(n0 + sn) * IN_F + skq;
    const int* fp = fine_idx + (size_t)(n0 + sn) * IN_F + skq;
    __syncthreads();
    int4 pb = *(const int4*)(bp);
    int4 pf = *(const int4*)(fp);
    {
        uint32 w0 = (uint32)sh_lut[(pb.x << 8) + pf.x] | ((uint32)sh_lut[(pb.y << 8) + pf.y] << 16);
        uint32 w1 = (uint32)sh_lut[(pb.z << 8) + pf.z] | ((uint32)sh_lut[(pb.w << 8) + pf.w] << 16);
        uint2 wv; wv.x = w0; wv.y = w1;
        *(uint2*)&sh_w[0][sn * WS + skq] = wv;
    }
    pb = *(const int4*)(bp + FBK);
    pf = *(const int4*)(fp + FBK);
    __syncthreads();
    const int lane = tid & 63;
    const int wave = tid >> 6;
    const int l16  = lane & 15;
    const int quad = lane >> 4;
    floatx4 acc[2][2];
    const floatx4 zero = {0.f, 0.f, 0.f, 0.f};
    acc[0][0] = zero; acc[0][1] = zero; acc[1][0] = zero; acc[1][1] = zero;
    const int mrow = wave * 32 + l16;
    const ushort_t* xrow  = XBF16 ? (xb + (size_t)mrow * IN_F + quad * 8) : (const ushort_t*)nullptr;
    const float*    xrowf = XBF16 ? (const float*)nullptr : (xf + (size_t)mrow * IN_F + quad * 8);
    for (int t = 0; t < NITER; ++t) {
        const int k0 = t * FBK;
        {
            uint32 w0 = (uint32)sh_lut[(pb.x << 8) + pf.x] | ((uint32)sh_lut[(pb.y << 8) + pf.y] << 16);
            uint32 w1 = (uint32)sh_lut[(pb.z << 8) + pf.z] | ((uint32)sh_lut[(pb.w << 8) + pf.w] << 16);
            uint2 wv; wv.x = w0; wv.y = w1;
            *(uint2*)&sh_w[(t + 1) & 1][sn * WS + skq] = wv;
        }
        {
            const int kk = (t + 2 < NITER ? t + 2 : NITER - 1) * FBK;
            pb = *(const int4*)(bp + kk);
            pf = *(const int4*)(fp + kk);
        }
        const ushort_t* wb = sh_w[t & 1];
#pragma unroll
        for (int ks = 0; ks < 4; ++ks) {
            const int kk = k0 + ks * 32;
            short8 b0 = *(const short8*)&wb[l16        * WS + ks * 32 + quad * 8];
            short8 b1 = *(const short8*)&wb[(16 + l16) * WS + ks * 32 + quad * 8];
            short8 a0, a1;
            if (XBF16) {
                a0 = *(const short8*)(xrow + kk);
                a1 = *(const short8*)(xrow + (size_t)16 * IN_F + kk);
            } else {
                const float* p0 = xrowf + kk;
                const float* p1 = xrowf + (size_t)16 * IN_F + kk;
                float4 u0 = *(const float4*)p0, u1 = *(const float4*)(p0 + 4);
                float4 v0 = *(const float4*)p1, v1 = *(const float4*)(p1 + 4);
                a0[0] = (short)f2bf(u0.x); a0[1] = (short)f2bf(u0.y);
                a0[2] = (short)f2bf(u0.z); a0[3] = (short)f2bf(u0.w);
                a0[4] = (short)f2bf(u1.x); a0[5] = (short)f2bf(u1.y);
                a0[6] = (short)f2bf(u1.z); a0[7] = (short)f2bf(u1.w);
                a1[0] = (short)f2bf(v0.x); a1[1] = (short)f2bf(v0.y);
                a1[2] = (short)f2bf(v0.z); a1[3] = (short)f2bf(v0.w);
                a1[4] = (short)f2bf(v1.x); a1[5] = (short)f2bf(v1.y);
                a1[6] = (short)f2bf(v1.z); a1[7] = (short)f2bf(v1.w);
            }
            acc[0][0] = __builtin_amdgcn_mfma_f32_16x16x32_bf16(a0, b0, acc[0][0], 0, 0, 0);
            acc[0][1] = __builtin_amdgcn_mfma_f32_16x16x32_bf16(a0, b1, acc[0][1], 0, 0, 0);
            acc[1][0] = __builtin_amdgcn_mfma_f32_16x16x32_bf16(a1, b0, acc[1][0], 0, 0, 0);
            acc[1][1] = __builtin_amdgcn_mfma_f32_16x16x32_bf16(a1, b1, acc[1][1], 0, 0, 0);
        }
        __syncthreads();
    }
#pragma unroll
    for (int nf = 0; nf < 2; ++nf) {
        const int col = n0 + nf * 16 + l16;
        const float sc = scale[col];
#pragma unroll
        for (int f = 0; f < 2; ++f) {
            const int r0 = wave * 32 + f * 16 + quad * 4;
#pragma unroll
            for (int r = 0; r < 4; ++r) {
                out[(size_t)(r0 + r) * OUT_F + col] = acc[f][nf][r] * sc;
            }
        }
    }
}

// ---------------------------------------------------------------------------
extern "C" void kernel_launch(void* const* d_in, const int* in_sizes, int n_in,
                              void* d_out, int out_size, void* d_ws, size_t ws_size,
                              hipStream_t stream) {
    const float* x      = (const float*)d_in[0];
    const int*   bidx   = (const int*)d_in[1];
    const int*   fidx   = (const int*)d_in[2];
    const float* scale  = (const float*)d_in[3];
    const float* lut    = (const float*)d_in[4];
    float*       out    = (float*)d_out;

    const size_t xb_bytes = (size_t)M_TOT * IN_F * sizeof(ushort_t);           // 4 MB
    const size_t wq_bytes = (size_t)OUT_F * IN_F * sizeof(ushort_t);           // 64 MB

    if (ws_size >= xb_bytes + wq_bytes) {
        ushort_t* xbuf = (ushort_t*)d_ws;
        ushort_t* wbuf = (ushort_t*)((char*)d_ws + xb_bytes);
        cvt_x_kernel<<<1024, 256, 0, stream>>>(x, xbuf);
        dequant_kernel<<<dim3(256, 2), 1024, 0, stream>>>(bidx, fidx, lut, wbuf);
        gemm_kernel<<<dim3(4, 64), 256, 0, stream>>>(xbuf, wbuf, scale, out);
    } else if (ws_size >= xb_bytes) {
        ushort_t* xbuf = (ushort_t*)d_ws;
        cvt_x_kernel<<<1024, 256, 0, stream>>>(x, xbuf);
        ghost_kernel<true><<<OUT_F / NB, 1024, 0, stream>>>(x, xbuf, bidx, fidx, scale, lut, out);
    } else {
        ghost_kernel<false><<<OUT_F / NB, 1024, 0, stream>>>(x, nullptr, bidx, fidx, scale, lut, out);
    }
}

// Round 6
// 364.670 us; speedup vs baseline: 1.0636x; 1.0636x over previous
//
#include <hip/hip_runtime.h>

typedef unsigned short ushort_t;
typedef unsigned int   uint32;
typedef __attribute__((ext_vector_type(8)))  short short8;    // 8 x bf16 (4 VGPRs)
typedef __attribute__((ext_vector_type(4)))  float floatx4;
typedef __attribute__((ext_vector_type(16))) float floatx16;  // 32x32 MFMA accumulator

#define IN_F   4096
#define OUT_F  8192
#define M_TOT  512

__device__ __forceinline__ ushort_t f2bf(float f) {
    uint32 u = __builtin_bit_cast(uint32, f);
    u += 0x7FFFu + ((u >> 16) & 1u);    // RNE
    return (ushort_t)(u >> 16);
}
__device__ __forceinline__ uint32 pack2bf(float a, float b) {
    return (uint32)f2bf(a) | ((uint32)f2bf(b) << 16);
}

// ---------------------------------------------------------------------------
// Kernel 0: x fp32 -> bf16 into workspace (4 MB).
__global__ void cvt_x_kernel(const float* __restrict__ x, ushort_t* __restrict__ xb) {
    int i = (blockIdx.x * 256 + threadIdx.x) * 8;
    float4 v0 = *(const float4*)(x + i);
    float4 v1 = *(const float4*)(x + i + 4);
    short8 s;
    s[0] = (short)f2bf(v0.x); s[1] = (short)f2bf(v0.y);
    s[2] = (short)f2bf(v0.z); s[3] = (short)f2bf(v0.w);
    s[4] = (short)f2bf(v1.x); s[5] = (short)f2bf(v1.y);
    s[6] = (short)f2bf(v1.z); s[7] = (short)f2bf(v1.w);
    *(short8*)(xb + i) = s;
}

// ---------------------------------------------------------------------------
// Kernel 1: dequant W -> bf16 [OUT_F][IN_F].  (unchanged from round 5 — it
// improved 105->~76 and is not this round's target.)
__global__ __launch_bounds__(1024, 4)
void dequant_kernel(const int* __restrict__ base_idx, const int* __restrict__ fine_idx,
                    const float* __restrict__ lut, ushort_t* __restrict__ wq)
{
    __shared__ ushort_t sh_lut[65536];   // 128 KB bf16 LUT
    const int tid = threadIdx.x;
    for (int i = tid * 4; i < 65536; i += 1024 * 4) {
        float4 v = *(const float4*)(lut + i);
        *(uint32*)&sh_lut[i]     = pack2bf(v.x, v.y);
        *(uint32*)&sh_lut[i + 2] = pack2bf(v.z, v.w);
    }

    const int row   = blockIdx.x * 32 + (tid >> 5);
    const int kbase = blockIdx.y * 2048 + (tid & 31) * 4;
    const int* bp = base_idx + (size_t)row * IN_F + kbase;
    const int* fp = fine_idx + (size_t)row * IN_F + kbase;
    ushort_t*  op = wq       + (size_t)row * IN_F + kbase;

    int4 cb[2][4], cf[2][4];
#pragma unroll
    for (int u = 0; u < 4; ++u) {
        cb[0][u] = *(const int4*)(bp + u * 128);
        cf[0][u] = *(const int4*)(fp + u * 128);
    }
#pragma unroll
    for (int u = 0; u < 4; ++u) {
        cb[1][u] = *(const int4*)(bp + (4 + u) * 128);
        cf[1][u] = *(const int4*)(fp + (4 + u) * 128);
    }
    __syncthreads();   // LUT ready (idx loads already in flight across it)

#pragma unroll
    for (int b = 0; b < 4; ++b) {
        const int cur = b & 1;
#pragma unroll
        for (int u = 0; u < 4; ++u) {
            uint32 w0 = (uint32)sh_lut[(cb[cur][u].x << 8) + cf[cur][u].x]
                      | ((uint32)sh_lut[(cb[cur][u].y << 8) + cf[cur][u].y] << 16);
            uint32 w1 = (uint32)sh_lut[(cb[cur][u].z << 8) + cf[cur][u].z]
                      | ((uint32)sh_lut[(cb[cur][u].w << 8) + cf[cur][u].w] << 16);
            uint2 wv; wv.x = w0; wv.y = w1;
            *(uint2*)(op + (size_t)(b * 4 + u) * 128) = wv;
        }
        if (b + 2 < 4) {
#pragma unroll
            for (int u = 0; u < 4; ++u) {
                cb[cur][u] = *(const int4*)(bp + ((b + 2) * 4 + u) * 128);
                cf[cur][u] = *(const int4*)(fp + ((b + 2) * 4 + u) * 128);
            }
        }
    }
}

// ---------------------------------------------------------------------------
// Kernel 2: K-split GEMM partials.  part[z][512,8192] = xb[:, zK:(z+1)K] *
// wq[:, zK:(z+1)K]^T, z=0,1, K=2048.  Grid (4,64,2) = 512 blocks -> 2
// blocks/CU (64 KB LDS), 8 waves/CU: one block's compute hides the other's
// barrier drain (m114 overlap) — the thing rounds 3-5 lacked at 1 block/CU.
// Phase-separated round-4 structure (known conflict-free), XOR-swizzled LDS.
#define BK 128
__global__ __launch_bounds__(256, 2)
void gemm_split_kernel(const ushort_t* __restrict__ xb, const ushort_t* __restrict__ wq,
                       float* __restrict__ part)
{
    __shared__ ushort_t shA[128 * BK];   // 32 KB
    __shared__ ushort_t shB[128 * BK];   // 32 KB

    const int tid  = threadIdx.x;
    const int wave = tid >> 6;
    const int m0   = blockIdx.x * 128;
    const int n0   = blockIdx.y * 128;
    const int kz   = blockIdx.z * (IN_F / 2);   // 0 or 2048

    // staging: inst i covers rows [i*16,+16); thread -> row tid>>4.
    // LDS dest (HW-fixed): wave base + lane*16 -> position chunk = lane&15.
    // Source chunk XOR-swizzled: g = (lane&15) ^ (row&7).
    const int g = (tid & 15) ^ ((tid >> 4) & 7);
    const ushort_t* aBase = xb + (size_t)(m0 + (tid >> 4)) * IN_F + kz + g * 8;
    const ushort_t* bBase = wq + (size_t)(n0 + (tid >> 4)) * IN_F + kz + g * 8;
    typedef __attribute__((address_space(3))) ushort_t lds_us;
    typedef const __attribute__((address_space(1))) void gvoid;
    lds_us* sA3 = (lds_us*)shA;
    lds_us* sB3 = (lds_us*)shB;

    const int lane = tid & 63;
    const int l31  = lane & 31;
    const int lhi  = lane >> 5;
    const int qm   = wave & 1;
    const int qn   = wave >> 1;
    const int rx   = l31 & 7;            // read-side XOR key (row&7)

    floatx16 acc[2][2];
    const floatx16 z16 = {0.f,0.f,0.f,0.f,0.f,0.f,0.f,0.f,0.f,0.f,0.f,0.f,0.f,0.f,0.f,0.f};
    acc[0][0] = z16; acc[0][1] = z16; acc[1][0] = z16; acc[1][1] = z16;

    for (int kb = 0; kb < IN_F / 2; kb += BK) {    // 16 iterations
#pragma unroll
        for (int i = 0; i < 8; ++i) {
            __builtin_amdgcn_global_load_lds((gvoid*)(aBase + (size_t)i * 16 * IN_F + kb),
                (__attribute__((address_space(3))) void*)(sA3 + i * 2048 + wave * 512),
                16, 0, 0);
            __builtin_amdgcn_global_load_lds((gvoid*)(bBase + (size_t)i * 16 * IN_F + kb),
                (__attribute__((address_space(3))) void*)(sB3 + i * 2048 + wave * 512),
                16, 0, 0);
        }
        __syncthreads();   // tiles visible

#pragma unroll
        for (int ks = 0; ks < 8; ++ks) {     // K-steps of 16
            const int p = ((2 * ks + lhi) ^ rx) * 8;   // swizzled chunk -> ushort offset
            short8 a0 = *(const short8*)&shA[(qm * 64 +      l31) * BK + p];
            short8 a1 = *(const short8*)&shA[(qm * 64 + 32 + l31) * BK + p];
            short8 b0 = *(const short8*)&shB[(qn * 64 +      l31) * BK + p];
            short8 b1 = *(const short8*)&shB[(qn * 64 + 32 + l31) * BK + p];
            acc[0][0] = __builtin_amdgcn_mfma_f32_32x32x16_bf16(a0, b0, acc[0][0], 0, 0, 0);
            acc[0][1] = __builtin_amdgcn_mfma_f32_32x32x16_bf16(a0, b1, acc[0][1], 0, 0, 0);
            acc[1][0] = __builtin_amdgcn_mfma_f32_32x32x16_bf16(a1, b0, acc[1][0], 0, 0, 0);
            acc[1][1] = __builtin_amdgcn_mfma_f32_32x32x16_bf16(a1, b1, acc[1][1], 0, 0, 0);
        }
        __syncthreads();   // all reads done before next staging
    }

    // epilogue: raw partial (scale applied in reduce).
    float* pz = part + (size_t)blockIdx.z * M_TOT * OUT_F;
#pragma unroll
    for (int nt = 0; nt < 2; ++nt) {
        const int col = n0 + qn * 64 + nt * 32 + l31;
#pragma unroll
        for (int mt = 0; mt < 2; ++mt) {
            const int rbase = m0 + qm * 64 + mt * 32 + 4 * lhi;
#pragma unroll
            for (int reg = 0; reg < 16; ++reg) {
                const int row = rbase + (reg & 3) + 8 * (reg >> 2);
                pz[(size_t)row * OUT_F + col] = acc[mt][nt][reg];
            }
        }
    }
}

// Kernel 3: out = (p0 + p1) * scale[col].  4.19M elems, float4, 4096 blocks.
__global__ void reduce_kernel(const float* __restrict__ p0, const float* __restrict__ p1,
                              const float* __restrict__ scale, float* __restrict__ out)
{
    const int i = (blockIdx.x * 256 + threadIdx.x) * 4;
    float4 a = *(const float4*)(p0 + i);
    float4 b = *(const float4*)(p1 + i);
    float4 s = *(const float4*)(scale + (i & (OUT_F - 1)));
    float4 r;
    r.x = (a.x + b.x) * s.x;
    r.y = (a.y + b.y) * s.y;
    r.z = (a.z + b.z) * s.z;
    r.w = (a.w + b.w) * s.w;
    *(float4*)(out + i) = r;
}

// ---------------------------------------------------------------------------
// Fallback A: round-4 single-shot GEMM (scale in epilogue) if ws lacks room
// for partials.
__global__ __launch_bounds__(256)
void gemm_full_kernel(const ushort_t* __restrict__ xb, const ushort_t* __restrict__ wq,
                      const float* __restrict__ scale, float* __restrict__ out)
{
    __shared__ ushort_t shA[128 * BK];
    __shared__ ushort_t shB[128 * BK];

    const int tid  = threadIdx.x;
    const int wave = tid >> 6;
    const int m0   = blockIdx.x * 128;
    const int n0   = blockIdx.y * 128;

    const int g = (tid & 15) ^ ((tid >> 4) & 7);
    const ushort_t* aBase = xb + (size_t)(m0 + (tid >> 4)) * IN_F + g * 8;
    const ushort_t* bBase = wq + (size_t)(n0 + (tid >> 4)) * IN_F + g * 8;
    typedef __attribute__((address_space(3))) ushort_t lds_us;
    typedef const __attribute__((address_space(1))) void gvoid;
    lds_us* sA3 = (lds_us*)shA;
    lds_us* sB3 = (lds_us*)shB;

    const int lane = tid & 63;
    const int l31  = lane & 31;
    const int lhi  = lane >> 5;
    const int qm   = wave & 1;
    const int qn   = wave >> 1;
    const int rx   = l31 & 7;

    floatx16 acc[2][2];
    const floatx16 z16 = {0.f,0.f,0.f,0.f,0.f,0.f,0.f,0.f,0.f,0.f,0.f,0.f,0.f,0.f,0.f,0.f};
    acc[0][0] = z16; acc[0][1] = z16; acc[1][0] = z16; acc[1][1] = z16;

    for (int kb = 0; kb < IN_F; kb += BK) {
#pragma unroll
        for (int i = 0; i < 8; ++i) {
            __builtin_amdgcn_global_load_lds((gvoid*)(aBase + (size_t)i * 16 * IN_F + kb),
                (__attribute__((address_space(3))) void*)(sA3 + i * 2048 + wave * 512), 16, 0, 0);
            __builtin_amdgcn_global_load_lds((gvoid*)(bBase + (size_t)i * 16 * IN_F + kb),
                (__attribute__((address_space(3))) void*)(sB3 + i * 2048 + wave * 512), 16, 0, 0);
        }
        __syncthreads();
#pragma unroll
        for (int ks = 0; ks < 8; ++ks) {
            const int p = ((2 * ks + lhi) ^ rx) * 8;
            short8 a0 = *(const short8*)&shA[(qm * 64 +      l31) * BK + p];
            short8 a1 = *(const short8*)&shA[(qm * 64 + 32 + l31) * BK + p];
            short8 b0 = *(const short8*)&shB[(qn * 64 +      l31) * BK + p];
            short8 b1 = *(const short8*)&shB[(qn * 64 + 32 + l31) * BK + p];
            acc[0][0] = __builtin_amdgcn_mfma_f32_32x32x16_bf16(a0, b0, acc[0][0], 0, 0, 0);
            acc[0][1] = __builtin_amdgcn_mfma_f32_32x32x16_bf16(a0, b1, acc[0][1], 0, 0, 0);
            acc[1][0] = __builtin_amdgcn_mfma_f32_32x32x16_bf16(a1, b0, acc[1][0], 0, 0, 0);
            acc[1][1] = __builtin_amdgcn_mfma_f32_32x32x16_bf16(a1, b1, acc[1][1], 0, 0, 0);
        }
        __syncthreads();
    }
#pragma unroll
    for (int nt = 0; nt < 2; ++nt) {
        const int col = n0 + qn * 64 + nt * 32 + l31;
        const float sc = scale[col];
#pragma unroll
        for (int mt = 0; mt < 2; ++mt) {
            const int rbase = m0 + qm * 64 + mt * 32 + 4 * lhi;
#pragma unroll
            for (int reg = 0; reg < 16; ++reg) {
                const int row = rbase + (reg & 3) + 8 * (reg >> 2);
                out[(size_t)row * OUT_F + col] = acc[mt][nt][reg] * sc;
            }
        }
    }
}

// ---------------------------------------------------------------------------
// Fallback B: round-2 fused kernel (workspace too small for wq).
#define NB  32
#define FBK 128
#define WS  136
#define NITER (IN_F / FBK)
template<bool XBF16>
__global__ __launch_bounds__(1024, 4)
void ghost_kernel(const float* __restrict__ xf, const ushort_t* __restrict__ xb,
                  const int* __restrict__ base_idx, const int* __restrict__ fine_idx,
                  const float* __restrict__ scale, const float* __restrict__ lut,
                  float* __restrict__ out)
{
    __shared__ ushort_t sh_lut[65536];
    __shared__ ushort_t sh_w[2][NB * WS];
    const int tid = threadIdx.x;
    const int n0  = blockIdx.x * NB;
    for (int i = tid * 4; i < 65536; i += 1024 * 4) {
        float4 v = *(const float4*)(lut + i);
        sh_lut[i + 0] = f2bf(v.x); sh_lut[i + 1] = f2bf(v.y);
        sh_lut[i + 2] = f2bf(v.z); sh_lut[i + 3] = f2bf(v.w);
    }
    const int sn  = tid >> 5;
    const int skq = (tid & 31) * 4;
    const int* bp = base_idx + (size_t)(n0 + sn) * IN_F + skq;
    const int* fp = fine_idx + (size_t)(n0 + sn) * IN_F + skq;
    __syncthreads();
    int4 pb = *(const int4*)(bp);
    int4 pf = *(const int4*)(fp);
    {
        uint32 w0 = (uint32)sh_lut[(pb.x << 8) + pf.x] | ((uint32)sh_lut[(pb.y << 8) + pf.y] << 16);
        uint32 w1 = (uint32)sh_lut[(pb.z << 8) + pf.z] | ((uint32)sh_lut[(pb.w << 8) + pf.w] << 16);
        uint2 wv; wv.x = w0; wv.y = w1;
        *(uint2*)&sh_w[0][sn * WS + skq] = wv;
    }
    pb = *(const int4*)(bp + FBK);
    pf = *(const int4*)(fp + FBK);
    __syncthreads();
    const int lane = tid & 63;
    const int wave = tid >> 6;
    const int l16  = lane & 15;
    const int quad = lane >> 4;
    floatx4 acc[2][2];
    const floatx4 zero = {0.f, 0.f, 0.f, 0.f};
    acc[0][0] = zero; acc[0][1] = zero; acc[1][0] = zero; acc[1][1] = zero;
    const int mrow = wave * 32 + l16;
    const ushort_t* xrow  = XBF16 ? (xb + (size_t)mrow * IN_F + quad * 8) : (const ushort_t*)nullptr;
    const float*    xrowf = XBF16 ? (const float*)nullptr : (xf + (size_t)mrow * IN_F + quad * 8);
    for (int t = 0; t < NITER; ++t) {
        const int k0 = t * FBK;
        {
            uint32 w0 = (uint32)sh_lut[(pb.x << 8) + pf.x] | ((uint32)sh_lut[(pb.y << 8) + pf.y] << 16);
            uint32 w1 = (uint32)sh_lut[(pb.z << 8) + pf.z] | ((uint32)sh_lut[(pb.w << 8) + pf.w] << 16);
            uint2 wv; wv.x = w0; wv.y = w1;
            *(uint2*)&sh_w[(t + 1) & 1][sn * WS + skq] = wv;
        }
        {
            const int kk = (t + 2 < NITER ? t + 2 : NITER - 1) * FBK;
            pb = *(const int4*)(bp + kk);
            pf = *(const int4*)(fp + kk);
        }
        const ushort_t* wb = sh_w[t & 1];
#pragma unroll
        for (int ks = 0; ks < 4; ++ks) {
            const int kk = k0 + ks * 32;
            short8 b0 = *(const short8*)&wb[l16        * WS + ks * 32 + quad * 8];
            short8 b1 = *(const short8*)&wb[(16 + l16) * WS + ks * 32 + quad * 8];
            short8 a0, a1;
            if (XBF16) {
                a0 = *(const short8*)(xrow + kk);
                a1 = *(const short8*)(xrow + (size_t)16 * IN_F + kk);
            } else {
                const float* p0 = xrowf + kk;
                const float* p1 = xrowf + (size_t)16 * IN_F + kk;
                float4 u0 = *(const float4*)p0, u1 = *(const float4*)(p0 + 4);
                float4 v0 = *(const float4*)p1, v1 = *(const float4*)(p1 + 4);
                a0[0] = (short)f2bf(u0.x); a0[1] = (short)f2bf(u0.y);
                a0[2] = (short)f2bf(u0.z); a0[3] = (short)f2bf(u0.w);
                a0[4] = (short)f2bf(u1.x); a0[5] = (short)f2bf(u1.y);
                a0[6] = (short)f2bf(u1.z); a0[7] = (short)f2bf(u1.w);
                a1[0] = (short)f2bf(v0.x); a1[1] = (short)f2bf(v0.y);
                a1[2] = (short)f2bf(v0.z); a1[3] = (short)f2bf(v0.w);
                a1[4] = (short)f2bf(v1.x); a1[5] = (short)f2bf(v1.y);
                a1[6] = (short)f2bf(v1.z); a1[7] = (short)f2bf(v1.w);
            }
            acc[0][0] = __builtin_amdgcn_mfma_f32_16x16x32_bf16(a0, b0, acc[0][0], 0, 0, 0);
            acc[0][1] = __builtin_amdgcn_mfma_f32_16x16x32_bf16(a0, b1, acc[0][1], 0, 0, 0);
            acc[1][0] = __builtin_amdgcn_mfma_f32_16x16x32_bf16(a1, b0, acc[1][0], 0, 0, 0);
            acc[1][1] = __builtin_amdgcn_mfma_f32_16x16x32_bf16(a1, b1, acc[1][1], 0, 0, 0);
        }
        __syncthreads();
    }
#pragma unroll
    for (int nf = 0; nf < 2; ++nf) {
        const int col = n0 + nf * 16 + l16;
        const float sc = scale[col];
#pragma unroll
        for (int f = 0; f < 2; ++f) {
            const int r0 = wave * 32 + f * 16 + quad * 4;
#pragma unroll
            for (int r = 0; r < 4; ++r) {
                out[(size_t)(r0 + r) * OUT_F + col] = acc[f][nf][r] * sc;
            }
        }
    }
}

// ---------------------------------------------------------------------------
extern "C" void kernel_launch(void* const* d_in, const int* in_sizes, int n_in,
                              void* d_out, int out_size, void* d_ws, size_t ws_size,
                              hipStream_t stream) {
    const float* x      = (const float*)d_in[0];
    const int*   bidx   = (const int*)d_in[1];
    const int*   fidx   = (const int*)d_in[2];
    const float* scale  = (const float*)d_in[3];
    const float* lut    = (const float*)d_in[4];
    float*       out    = (float*)d_out;

    const size_t xb_bytes = (size_t)M_TOT * IN_F * sizeof(ushort_t);   // 4 MB
    const size_t wq_bytes = (size_t)OUT_F * IN_F * sizeof(ushort_t);   // 64 MB
    const size_t pt_bytes = (size_t)M_TOT * OUT_F * sizeof(float);     // 16.8 MB each

    if (ws_size >= xb_bytes + wq_bytes + 2 * pt_bytes) {
        ushort_t* xbuf = (ushort_t*)d_ws;
        ushort_t* wbuf = (ushort_t*)((char*)d_ws + xb_bytes);
        float*    part = (float*)((char*)d_ws + xb_bytes + wq_bytes);
        cvt_x_kernel<<<1024, 256, 0, stream>>>(x, xbuf);
        dequant_kernel<<<dim3(256, 2), 1024, 0, stream>>>(bidx, fidx, lut, wbuf);
        gemm_split_kernel<<<dim3(4, 64, 2), 256, 0, stream>>>(xbuf, wbuf, part);
        reduce_kernel<<<(M_TOT * OUT_F) / (256 * 4), 256, 0, stream>>>(
            part, part + (size_t)M_TOT * OUT_F, scale, out);
    } else if (ws_size >= xb_bytes + wq_bytes) {
        ushort_t* xbuf = (ushort_t*)d_ws;
        ushort_t* wbuf = (ushort_t*)((char*)d_ws + xb_bytes);
        cvt_x_kernel<<<1024, 256, 0, stream>>>(x, xbuf);
        dequant_kernel<<<dim3(256, 2), 1024, 0, stream>>>(bidx, fidx, lut, wbuf);
        gemm_full_kernel<<<dim3(4, 64), 256, 0, stream>>>(xbuf, wbuf, scale, out);
    } else if (ws_size >= xb_bytes) {
        ushort_t* xbuf = (ushort_t*)d_ws;
        cvt_x_kernel<<<1024, 256, 0, stream>>>(x, xbuf);
        ghost_kernel<true><<<OUT_F / NB, 1024, 0, stream>>>(x, xbuf, bidx, fidx, scale, lut, out);
    } else {
        ghost_kernel<false><<<OUT_F / NB, 1024, 0, stream>>>(x, nullptr, bidx, fidx, scale, lut, out);
    }
}